// Round 6
// baseline (174.506 us; speedup 1.0000x reference)
//
#include <hip/hip_runtime.h>
#include <hip/hip_bf16.h>

#define N_FEAT 128     // D_FEAT == UNITS == 128
#define EPT 8          // edges per thread in partition passes
#define CHUNK 2048     // 256 threads * EPT
#define BSHIFT 8       // bucket = node >> 8  (bucket range = 256 nodes)
#define MAXRANGE 256
#define CAP 8192       // per-bucket slot capacity (expected 4096 +- 64; 60-sigma margin)
#define LSTR 66        // LDS row stride in dwords for staged GEMM tiles

typedef short bf16x8 __attribute__((ext_vector_type(8)));
typedef float f32x4  __attribute__((ext_vector_type(4)));

__device__ __forceinline__ unsigned short f2bf_rtne(float f) {
    unsigned u = __float_as_uint(f);
    u += 0x7fffu + ((u >> 16) & 1u);
    return (unsigned short)(u >> 16);
}
__device__ __forceinline__ float bf2f(unsigned short h) {
    return __uint_as_float((unsigned)h << 16);
}

// ---------------------------------------------------------------------------
// K1: scatter into fixed-capacity buckets (R10-proven body, verbatim) PLUS
// 8 extra blocks doing the W hi/lo split (moved from K2 so K2's GEMM pass
// can consume Whi/Wlo).
// ---------------------------------------------------------------------------
__global__ __launch_bounds__(256) void scatter_kernel(const int* __restrict__ source,
                                                      const int* __restrict__ target,
                                                      int* __restrict__ curT,
                                                      int* __restrict__ curS,
                                                      unsigned int* __restrict__ pairsT,
                                                      unsigned char* __restrict__ srcB,
                                                      const float* __restrict__ W,
                                                      unsigned short* __restrict__ Whi,
                                                      unsigned short* __restrict__ Wlo,
                                                      int E, int NB, int NBLK) {
    __shared__ unsigned int   lds_pairs[CHUNK];    // 8 KB
    __shared__ unsigned short lds_sp[CHUNK];       // 4 KB (low16 of s)
    __shared__ int ct[MAXRANGE], cs[MAXRANGE];
    __shared__ int st[MAXRANGE], ss[MAXRANGE];
    __shared__ int gt[MAXRANGE], gs[MAXRANGE];
    int tid = threadIdx.x, b = blockIdx.x;

    if (b >= NBLK) {
        // ---- W -> bf16 hi/lo in MFMA fragment order (verbatim K2-C) ----
        int idx = (b - NBLK) * 256 + tid;
        int lane = idx & 63;
        int ks = (idx >> 6) & 3;
        int ct2 = idx >> 8;
        int n  = ct2 * 16 + (lane & 15);
        int k0 = ks * 32 + (lane >> 4) * 8;
        unsigned short h[8], l[8];
        #pragma unroll
        for (int j = 0; j < 8; ++j) {
            float w = W[(k0 + j) * N_FEAT + n];
            unsigned short hh = f2bf_rtne(w);
            h[j] = hh;
            l[j] = f2bf_rtne(w - bf2f(hh));
        }
        size_t off = (size_t)idx * 8;
        *(ushort4*)(Whi + off)     = make_ushort4(h[0], h[1], h[2], h[3]);
        *(ushort4*)(Whi + off + 4) = make_ushort4(h[4], h[5], h[6], h[7]);
        *(ushort4*)(Wlo + off)     = make_ushort4(l[0], l[1], l[2], l[3]);
        *(ushort4*)(Wlo + off + 4) = make_ushort4(l[4], l[5], l[6], l[7]);
        return;
    }

    int base = b * CHUNK;
    int cnt = E - base; if (cnt > CHUNK) cnt = CHUNK;

    int rs[EPT], rt[EPT];
    ct[tid] = 0; cs[tid] = 0;
    __syncthreads();
    #pragma unroll
    for (int j = 0; j < EPT; ++j) {
        int e = base + j * 256 + tid;
        if (e < E) {
            int s = source[e], t = target[e];
            rs[j] = s; rt[j] = t;
            atomicAdd(&ct[t >> BSHIFT], 1);
            atomicAdd(&cs[s >> BSHIFT], 1);
        }
    }
    __syncthreads();
    int vt = ct[tid], vs = cs[tid];
    st[tid] = vt; ss[tid] = vs;
    __syncthreads();
    #pragma unroll
    for (int off = 1; off < 256; off <<= 1) {
        int t1 = (tid >= off) ? st[tid - off] : 0;
        int t2 = (tid >= off) ? ss[tid - off] : 0;
        __syncthreads();
        st[tid] += t1; ss[tid] += t2;
        __syncthreads();
    }
    int et = st[tid] - vt, es = ss[tid] - vs;
    int gT = 0, gS = 0;
    if (tid < NB) {
        if (vt) gT = atomicAdd(&curT[tid], vt);
        if (vs) gS = atomicAdd(&curS[tid], vs);
    }
    __syncthreads();
    st[tid] = et; ss[tid] = es;
    ct[tid] = et; cs[tid] = es;
    gt[tid] = gT; gs[tid] = gS;
    __syncthreads();
    #pragma unroll
    for (int j = 0; j < EPT; ++j) {
        int e = base + j * 256 + tid;
        if (e < E) {
            int s = rs[j], t = rt[j];
            int k = t >> BSHIFT;
            int p = atomicAdd(&ct[k], 1);
            lds_pairs[p] = (unsigned)s | ((unsigned)t << 16);
            int k2 = s >> BSHIFT;
            int p2 = atomicAdd(&cs[k2], 1);
            lds_sp[p2] = (unsigned short)s;
        }
    }
    __syncthreads();
    for (int i = tid; i < cnt; i += 256) {
        unsigned w = lds_pairs[i];
        int k = w >> 24;
        pairsT[(size_t)k * CAP + gt[k] + (i - st[k])] = w;
        unsigned short sp = lds_sp[i];
        int k2 = sp >> 8;
        srcB[(size_t)k2 * CAP + gs[k2] + (i - ss[k2])] = (unsigned char)sp;
    }
}

// ---------------------------------------------------------------------------
// K2: fused prep, R16. Pass A' (b < NB): out-degree hist (verbatim) then
// Y = diag(s) * X * W computed per 16-row tile with the PROVEN hi/lo 3-MFMA
// scheme from the old K3 phase 2; Y stored bf16 (replaces xb). Pass B
// (b >= NB): target CSR, verbatim R10.
// ---------------------------------------------------------------------------
__global__ __launch_bounds__(256) void prep_kernel(const unsigned char* __restrict__ srcB,
                                                   const unsigned int* __restrict__ pairsT,
                                                   const int* __restrict__ curT,
                                                   const int* __restrict__ curS,
                                                   const float* __restrict__ x,
                                                   const unsigned short* __restrict__ Whi,
                                                   const unsigned short* __restrict__ Wlo,
                                                   unsigned short* __restrict__ Y,
                                                   int2* __restrict__ offs,
                                                   int* __restrict__ elist,
                                                   float* __restrict__ ri,
                                                   int N, int NB) {
    __shared__ int hist[MAXRANGE];
    __shared__ int sb[MAXRANGE];
    __shared__ int excl[MAXRANGE];
    __shared__ int cur[MAXRANGE];
    __shared__ float so_l[MAXRANGE];
    __shared__ unsigned int hi_t[16 * LSTR];   // 4.2 KB staged A tile (hi)
    __shared__ unsigned int lo_t[16 * LSTR];   // 4.2 KB staged A tile (lo)
    int tid = threadIdx.x, b = blockIdx.x;
    int wave = tid >> 6, lane = tid & 63;
    int quad = lane >> 4, k16 = lane & 15;

    if (b < NB) {
        // ---- out-degree -> so_l (verbatim) ----
        hist[tid] = 0;
        __syncthreads();
        int cnt = curS[b];
        size_t base = (size_t)b * CAP;
        for (int i = tid; i < cnt; i += 256)
            atomicAdd(&hist[srcB[base + i]], 1);
        __syncthreads();
        {
            int d = hist[tid]; if (d < 1) d = 1;
            so_l[tid] = rsqrtf((float)d);
        }
        __syncthreads();
        // ---- Y = (s*x) @ W, 16-row tiles, hi/lo 3-MFMA (proven scheme) ----
        int row0 = b << BSHIFT;
        int nrows = N - row0; if (nrows > 256) nrows = 256;
        if (nrows <= 0) return;
        const bf16x8* BH = (const bf16x8*)Whi;
        const bf16x8* BL = (const bf16x8*)Wlo;
        for (int t0 = 0; t0 < nrows; t0 += 16) {
            for (int i = tid; i < 1024; i += 256) {      // 16 rows x 64 dwords
                int r = i >> 6, dw = i & 63;
                int gr = row0 + t0 + r;
                float s = so_l[t0 + r];
                float2 v = make_float2(0.f, 0.f);
                if (gr < N) v = ((const float2*)x)[(size_t)gr * 64 + dw];
                float v0 = s * v.x, v1 = s * v.y;
                unsigned short h0 = f2bf_rtne(v0), h1 = f2bf_rtne(v1);
                unsigned short l0 = f2bf_rtne(v0 - bf2f(h0));
                unsigned short l1 = f2bf_rtne(v1 - bf2f(h1));
                hi_t[r * LSTR + dw] = (unsigned)h0 | ((unsigned)h1 << 16);
                lo_t[r * LSTR + dw] = (unsigned)l0 | ((unsigned)l1 << 16);
            }
            __syncthreads();
            bf16x8 Ahi[4], Alo[4];
            int m = k16;
            #pragma unroll
            for (int ks = 0; ks < 4; ++ks) {
                int a = m * LSTR + ks * 16 + quad * 4;
                Ahi[ks] = *(const bf16x8*)(hi_t + a);
                Alo[ks] = *(const bf16x8*)(lo_t + a);
            }
            #pragma unroll
            for (int c = 0; c < 2; ++c) {
                int ctile = wave * 2 + c;
                f32x4 acc = {0.f, 0.f, 0.f, 0.f};
                #pragma unroll
                for (int ks = 0; ks < 4; ++ks) {
                    bf16x8 bh = BH[(ctile * 4 + ks) * 64 + lane];
                    bf16x8 bl = BL[(ctile * 4 + ks) * 64 + lane];
                    acc = __builtin_amdgcn_mfma_f32_16x16x32_bf16(Ahi[ks], bh, acc, 0, 0, 0);
                    acc = __builtin_amdgcn_mfma_f32_16x16x32_bf16(Alo[ks], bh, acc, 0, 0, 0);
                    acc = __builtin_amdgcn_mfma_f32_16x16x32_bf16(Ahi[ks], bl, acc, 0, 0, 0);
                }
                int colc = ctile * 16 + m;
                #pragma unroll
                for (int reg = 0; reg < 4; ++reg) {
                    int gr = row0 + t0 + quad * 4 + reg;
                    if (gr < N)
                        Y[(size_t)gr * N_FEAT + colc] = f2bf_rtne(acc[reg]);
                }
            }
            __syncthreads();
        }
    } else {
        // ---- pass B: per-bucket target CSR (verbatim R10) ----
        int bb = b - NB;
        hist[tid] = 0; cur[tid] = 0;
        __syncthreads();
        int cnt = curT[bb];
        int gbase = bb * CAP;
        for (int i = tid; i < cnt; i += 256)
            atomicAdd(&hist[(pairsT[(size_t)gbase + i] >> 16) & 255], 1);
        __syncthreads();
        int deg = hist[tid];
        sb[tid] = deg;
        __syncthreads();
        #pragma unroll
        for (int off = 1; off < 256; off <<= 1) {
            int t = (tid >= off) ? sb[tid - off] : 0;
            __syncthreads();
            sb[tid] += t;
            __syncthreads();
        }
        excl[tid] = sb[tid] - deg;
        __syncthreads();
        int node = (bb << BSHIFT) + tid;
        if (node < N) {
            int st0 = gbase + excl[tid];
            offs[node] = make_int2(st0, st0 + deg);
            int d = deg; if (d < 1) d = 1;
            ri[node] = rsqrtf((float)d);
        }
        for (int i = tid; i < cnt; i += 256) {
            unsigned w = pairsT[(size_t)gbase + i];
            int tl = (w >> 16) & 255;
            int pos = atomicAdd(&cur[tl], 1);
            elist[gbase + excl[tl] + pos] = (int)(w & 0xFFFFu);
        }
    }
}

#define ACC8(u) { acc[0] += __uint_as_float((u).x << 16); \
                  acc[1] += __uint_as_float((u).x & 0xffff0000u); \
                  acc[2] += __uint_as_float((u).y << 16); \
                  acc[3] += __uint_as_float((u).y & 0xffff0000u); \
                  acc[4] += __uint_as_float((u).z << 16); \
                  acc[5] += __uint_as_float((u).z & 0xffff0000u); \
                  acc[6] += __uint_as_float((u).w << 16); \
                  acc[7] += __uint_as_float((u).w & 0xffff0000u); }

// ---------------------------------------------------------------------------
// K3, R16: PURE gather-aggregate over Y (GEMM already applied). 128-thread
// 2-wave blocks, quad-per-node (8 nodes/block), 8-deep uint4 gathers, f32
// accumulate, scale+bias+relu, direct coalesced f32 store. NO LDS, NO
// barriers, NO MFMA, NO W traffic: the wave's entire life is the gather
// chain, and 6250 small blocks keep the CU full of gathering waves. This is
// also the discriminating experiment: >4 TB/s here = the old K3 was
// phase-structure-bound; ~2.2 TB/s = random-gather service ceiling (next
// step would be L2-resident feature-slice tiling).
// ---------------------------------------------------------------------------
__global__ __launch_bounds__(128) void agg_kernel(const unsigned short* __restrict__ Y,
                                                  const int* __restrict__ elist,
                                                  const int2* __restrict__ offs,
                                                  const float* __restrict__ ri,
                                                  const float* __restrict__ bias,
                                                  float* __restrict__ out,
                                                  int N) {
    int tid  = threadIdx.x;
    int wave = tid >> 6, lane = tid & 63;
    int quad = lane >> 4, k16 = lane & 15;
    int node = blockIdx.x * 8 + wave * 4 + quad;
    if (node >= N) return;
    const uint4* yr = (const uint4*)Y;     // 16 granules (uint4) per 128-feat row
    int2 oe = offs[node];
    float rr = ri[node];
    float acc[8] = {0.f, 0.f, 0.f, 0.f, 0.f, 0.f, 0.f, 0.f};
    int j = oe.x, je = oe.y;
    for (; j + 8 <= je; j += 8) {
        int e0 = elist[j],     e1 = elist[j + 1];
        int e2 = elist[j + 2], e3 = elist[j + 3];
        int e4 = elist[j + 4], e5 = elist[j + 5];
        int e6 = elist[j + 6], e7 = elist[j + 7];
        uint4 u0 = yr[(size_t)e0 * 16 + k16];
        uint4 u1 = yr[(size_t)e1 * 16 + k16];
        uint4 u2 = yr[(size_t)e2 * 16 + k16];
        uint4 u3 = yr[(size_t)e3 * 16 + k16];
        uint4 u4 = yr[(size_t)e4 * 16 + k16];
        uint4 u5 = yr[(size_t)e5 * 16 + k16];
        uint4 u6 = yr[(size_t)e6 * 16 + k16];
        uint4 u7 = yr[(size_t)e7 * 16 + k16];
        ACC8(u0) ACC8(u1) ACC8(u2) ACC8(u3)
        ACC8(u4) ACC8(u5) ACC8(u6) ACC8(u7)
    }
    for (; j < je; ++j) {
        int e = elist[j];
        uint4 u = yr[(size_t)e * 16 + k16];
        ACC8(u)
    }
    int f0 = k16 * 8;
    const float4* bp = (const float4*)(bias + f0);
    float4 b0 = bp[0], b1 = bp[1];
    float4 o0, o1;
    o0.x = fmaxf(acc[0] * rr + b0.x, 0.f);
    o0.y = fmaxf(acc[1] * rr + b0.y, 0.f);
    o0.z = fmaxf(acc[2] * rr + b0.z, 0.f);
    o0.w = fmaxf(acc[3] * rr + b0.w, 0.f);
    o1.x = fmaxf(acc[4] * rr + b1.x, 0.f);
    o1.y = fmaxf(acc[5] * rr + b1.y, 0.f);
    o1.z = fmaxf(acc[6] * rr + b1.z, 0.f);
    o1.w = fmaxf(acc[7] * rr + b1.w, 0.f);
    float4* op = (float4*)(out + (size_t)node * N_FEAT + f0);
    op[0] = o0;
    op[1] = o1;
}

// ---------------------------------------------------------------------------
extern "C" void kernel_launch(void* const* d_in, const int* in_sizes, int n_in,
                              void* d_out, int out_size, void* d_ws, size_t ws_size,
                              hipStream_t stream) {
    const float* x      = (const float*)d_in[0];
    const int*   source = (const int*)d_in[1];
    const int*   target = (const int*)d_in[2];
    const float* W      = (const float*)d_in[3];
    const float* bias   = (const float*)d_in[4];
    float*       out    = (float*)d_out;

    const int N = in_sizes[0] / N_FEAT;   // 50000
    const int E = in_sizes[1];            // 800000

    const int NB   = (N + MAXRANGE - 1) >> BSHIFT;  // 196
    const int NBLK = (E + CHUNK - 1) / CHUNK;       // 391

    uintptr_t p = (uintptr_t)d_ws;
    auto carve = [&](size_t bytes) {
        p = (p + 255) & ~(uintptr_t)255;
        uintptr_t r = p;
        p += bytes;
        return (void*)r;
    };
    int*            curs    = (int*)carve((size_t)2 * NB * sizeof(int)); // curT|curS (memset)
    int*            curT    = curs;
    int*            curS    = curs + NB;
    unsigned int*   pairsT  = (unsigned int*)carve((size_t)NB * CAP * sizeof(unsigned int));
    int*            elist   = (int*)carve((size_t)NB * CAP * sizeof(int));
    unsigned char*  srcB    = (unsigned char*)carve((size_t)NB * CAP);
    float*          ri      = (float*)carve((size_t)N * sizeof(float));
    int2*           offs    = (int2*)carve((size_t)N * sizeof(int2));
    unsigned short* Y       = (unsigned short*)carve((size_t)N * N_FEAT * sizeof(unsigned short));
    unsigned short* Whi     = (unsigned short*)carve((size_t)N_FEAT * N_FEAT * sizeof(unsigned short));
    unsigned short* Wlo     = (unsigned short*)carve((size_t)N_FEAT * N_FEAT * sizeof(unsigned short));
    (void)ws_size; (void)n_in; (void)out_size;

    (void)hipMemsetAsync(curs, 0, (size_t)2 * NB * sizeof(int), stream);

    scatter_kernel<<<NBLK + 8, 256, 0, stream>>>(source, target, curT, curS, pairsT, srcB,
                                                 W, Whi, Wlo, E, NB, NBLK);
    prep_kernel<<<2 * NB, 256, 0, stream>>>(srcB, pairsT, curT, curS, x, Whi, Wlo,
                                            Y, offs, elist, ri, N, NB);
    agg_kernel<<<(N + 7) / 8, 128, 0, stream>>>(Y, elist, offs, ri, bias, out, N);
}

// Round 7
// 159.142 us; speedup vs baseline: 1.0965x; 1.0965x over previous
//
#include <hip/hip_runtime.h>
#include <hip/hip_bf16.h>

#define N_FEAT 128     // D_FEAT == UNITS == 128
#define EPT 8          // edges per thread in partition passes
#define CHUNK 2048     // 256 threads * EPT
#define BSHIFT 8       // bucket = node >> 8  (bucket range = 256 nodes)
#define MAXRANGE 256
#define CAP 8192       // per-bucket slot capacity (expected 4096 +- 64; 60-sigma margin)
#define LSTR 66        // LDS row stride in dwords for staged GEMM tiles

typedef short bf16x8 __attribute__((ext_vector_type(8)));
typedef float f32x4  __attribute__((ext_vector_type(4)));

__device__ __forceinline__ unsigned short f2bf_rtne(float f) {
    unsigned u = __float_as_uint(f);
    u += 0x7fffu + ((u >> 16) & 1u);
    return (unsigned short)(u >> 16);
}
__device__ __forceinline__ float bf2f(unsigned short h) {
    return __uint_as_float((unsigned)h << 16);
}

// ---------------------------------------------------------------------------
// K1: scatter into fixed-capacity buckets (R10-proven body) + 8 extra
// blocks doing the W hi/lo split (unchanged from R16).
// ---------------------------------------------------------------------------
__global__ __launch_bounds__(256) void scatter_kernel(const int* __restrict__ source,
                                                      const int* __restrict__ target,
                                                      int* __restrict__ curT,
                                                      int* __restrict__ curS,
                                                      unsigned int* __restrict__ pairsT,
                                                      unsigned char* __restrict__ srcB,
                                                      const float* __restrict__ W,
                                                      unsigned short* __restrict__ Whi,
                                                      unsigned short* __restrict__ Wlo,
                                                      int E, int NB, int NBLK) {
    __shared__ unsigned int   lds_pairs[CHUNK];    // 8 KB
    __shared__ unsigned short lds_sp[CHUNK];       // 4 KB (low16 of s)
    __shared__ int ct[MAXRANGE], cs[MAXRANGE];
    __shared__ int st[MAXRANGE], ss[MAXRANGE];
    __shared__ int gt[MAXRANGE], gs[MAXRANGE];
    int tid = threadIdx.x, b = blockIdx.x;

    if (b >= NBLK) {
        // ---- W -> bf16 hi/lo in MFMA fragment order ----
        int idx = (b - NBLK) * 256 + tid;
        int lane = idx & 63;
        int ks = (idx >> 6) & 3;
        int ct2 = idx >> 8;
        int n  = ct2 * 16 + (lane & 15);
        int k0 = ks * 32 + (lane >> 4) * 8;
        unsigned short h[8], l[8];
        #pragma unroll
        for (int j = 0; j < 8; ++j) {
            float w = W[(k0 + j) * N_FEAT + n];
            unsigned short hh = f2bf_rtne(w);
            h[j] = hh;
            l[j] = f2bf_rtne(w - bf2f(hh));
        }
        size_t off = (size_t)idx * 8;
        *(ushort4*)(Whi + off)     = make_ushort4(h[0], h[1], h[2], h[3]);
        *(ushort4*)(Whi + off + 4) = make_ushort4(h[4], h[5], h[6], h[7]);
        *(ushort4*)(Wlo + off)     = make_ushort4(l[0], l[1], l[2], l[3]);
        *(ushort4*)(Wlo + off + 4) = make_ushort4(l[4], l[5], l[6], l[7]);
        return;
    }

    int base = b * CHUNK;
    int cnt = E - base; if (cnt > CHUNK) cnt = CHUNK;

    int rs[EPT], rt[EPT];
    ct[tid] = 0; cs[tid] = 0;
    __syncthreads();
    #pragma unroll
    for (int j = 0; j < EPT; ++j) {
        int e = base + j * 256 + tid;
        if (e < E) {
            int s = source[e], t = target[e];
            rs[j] = s; rt[j] = t;
            atomicAdd(&ct[t >> BSHIFT], 1);
            atomicAdd(&cs[s >> BSHIFT], 1);
        }
    }
    __syncthreads();
    int vt = ct[tid], vs = cs[tid];
    st[tid] = vt; ss[tid] = vs;
    __syncthreads();
    #pragma unroll
    for (int off = 1; off < 256; off <<= 1) {
        int t1 = (tid >= off) ? st[tid - off] : 0;
        int t2 = (tid >= off) ? ss[tid - off] : 0;
        __syncthreads();
        st[tid] += t1; ss[tid] += t2;
        __syncthreads();
    }
    int et = st[tid] - vt, es = ss[tid] - vs;
    int gT = 0, gS = 0;
    if (tid < NB) {
        if (vt) gT = atomicAdd(&curT[tid], vt);
        if (vs) gS = atomicAdd(&curS[tid], vs);
    }
    __syncthreads();
    st[tid] = et; ss[tid] = es;
    ct[tid] = et; cs[tid] = es;
    gt[tid] = gT; gs[tid] = gS;
    __syncthreads();
    #pragma unroll
    for (int j = 0; j < EPT; ++j) {
        int e = base + j * 256 + tid;
        if (e < E) {
            int s = rs[j], t = rt[j];
            int k = t >> BSHIFT;
            int p = atomicAdd(&ct[k], 1);
            lds_pairs[p] = (unsigned)s | ((unsigned)t << 16);
            int k2 = s >> BSHIFT;
            int p2 = atomicAdd(&cs[k2], 1);
            lds_sp[p2] = (unsigned short)s;
        }
    }
    __syncthreads();
    for (int i = tid; i < cnt; i += 256) {
        unsigned w = lds_pairs[i];
        int k = w >> 24;
        pairsT[(size_t)k * CAP + gt[k] + (i - st[k])] = w;
        unsigned short sp = lds_sp[i];
        int k2 = sp >> 8;
        srcB[(size_t)k2 * CAP + gs[k2] + (i - ss[k2])] = (unsigned char)sp;
    }
}

// ---------------------------------------------------------------------------
// K2: prep, R17. Pass A (b < NB): out-degree hist -> so[] to GLOBAL (the
// Y-GEMM moved out to its own well-parallelized kernel; R16's mistake was
// running it on 196 blocks at 7% occupancy). Pass B: target CSR, verbatim.
// ---------------------------------------------------------------------------
__global__ __launch_bounds__(256) void prep_kernel(const unsigned char* __restrict__ srcB,
                                                   const unsigned int* __restrict__ pairsT,
                                                   const int* __restrict__ curT,
                                                   const int* __restrict__ curS,
                                                   float* __restrict__ so,
                                                   int2* __restrict__ offs,
                                                   int* __restrict__ elist,
                                                   float* __restrict__ ri,
                                                   int N, int NB) {
    __shared__ int hist[MAXRANGE];
    __shared__ int sb[MAXRANGE];
    __shared__ int excl[MAXRANGE];
    __shared__ int cur[MAXRANGE];
    int tid = threadIdx.x, b = blockIdx.x;

    if (b < NB) {
        hist[tid] = 0;
        __syncthreads();
        int cnt = curS[b];
        size_t base = (size_t)b * CAP;
        for (int i = tid; i < cnt; i += 256)
            atomicAdd(&hist[srcB[base + i]], 1);
        __syncthreads();
        int node = (b << BSHIFT) + tid;
        if (node < N) {
            int d = hist[tid]; if (d < 1) d = 1;
            so[node] = rsqrtf((float)d);
        }
    } else {
        int bb = b - NB;
        hist[tid] = 0; cur[tid] = 0;
        __syncthreads();
        int cnt = curT[bb];
        int gbase = bb * CAP;
        for (int i = tid; i < cnt; i += 256)
            atomicAdd(&hist[(pairsT[(size_t)gbase + i] >> 16) & 255], 1);
        __syncthreads();
        int deg = hist[tid];
        sb[tid] = deg;
        __syncthreads();
        #pragma unroll
        for (int off = 1; off < 256; off <<= 1) {
            int t = (tid >= off) ? sb[tid - off] : 0;
            __syncthreads();
            sb[tid] += t;
            __syncthreads();
        }
        excl[tid] = sb[tid] - deg;
        __syncthreads();
        int node = (bb << BSHIFT) + tid;
        if (node < N) {
            int st0 = gbase + excl[tid];
            offs[node] = make_int2(st0, st0 + deg);
            int d = deg; if (d < 1) d = 1;
            ri[node] = rsqrtf((float)d);
        }
        for (int i = tid; i < cnt; i += 256) {
            unsigned w = pairsT[(size_t)gbase + i];
            int tl = (w >> 16) & 255;
            int pos = atomicAdd(&cur[tl], 1);
            elist[gbase + excl[tl] + pos] = (int)(w & 0xFFFFu);
        }
    }
}

// ---------------------------------------------------------------------------
// K3: Y = diag(so) * X * W, R17. One 16-row tile per block (3125 blocks,
// full occupancy) using the PROVEN hi/lo 3-MFMA scheme. Reads x f32 + so,
// writes Y bf16. ~38 MB traffic -> expect ~8-12 us.
// ---------------------------------------------------------------------------
__global__ __launch_bounds__(256) void ygemm_kernel(const float* __restrict__ x,
                                                    const float* __restrict__ so,
                                                    const unsigned short* __restrict__ Whi,
                                                    const unsigned short* __restrict__ Wlo,
                                                    unsigned short* __restrict__ Y,
                                                    int N) {
    __shared__ unsigned int hi_t[16 * LSTR];   // 4.2 KB
    __shared__ unsigned int lo_t[16 * LSTR];   // 4.2 KB
    int tid = threadIdx.x;
    int wave = tid >> 6, lane = tid & 63;
    int quad = lane >> 4, k16 = lane & 15;
    int row0 = blockIdx.x * 16;

    // ---- stage 16 rows of s*x as hi/lo bf16 (coalesced float2 loads) ----
    for (int i = tid; i < 1024; i += 256) {        // 16 rows x 64 float2
        int r = i >> 6, dw = i & 63;
        int gr = row0 + r;
        float2 v = make_float2(0.f, 0.f);
        float s = 0.f;
        if (gr < N) {
            v = ((const float2*)x)[(size_t)gr * 64 + dw];
            s = so[gr];
        }
        float v0 = s * v.x, v1 = s * v.y;
        unsigned short h0 = f2bf_rtne(v0), h1 = f2bf_rtne(v1);
        unsigned short l0 = f2bf_rtne(v0 - bf2f(h0));
        unsigned short l1 = f2bf_rtne(v1 - bf2f(h1));
        hi_t[r * LSTR + dw] = (unsigned)h0 | ((unsigned)h1 << 16);
        lo_t[r * LSTR + dw] = (unsigned)l0 | ((unsigned)l1 << 16);
    }
    __syncthreads();

    // ---- 16x128 MFMA tile (proven) ----
    bf16x8 Ahi[4], Alo[4];
    int m = k16;
    #pragma unroll
    for (int ks = 0; ks < 4; ++ks) {
        int a = m * LSTR + ks * 16 + quad * 4;
        Ahi[ks] = *(const bf16x8*)(hi_t + a);
        Alo[ks] = *(const bf16x8*)(lo_t + a);
    }
    const bf16x8* BH = (const bf16x8*)Whi;
    const bf16x8* BL = (const bf16x8*)Wlo;
    #pragma unroll
    for (int c = 0; c < 2; ++c) {
        int ctile = wave * 2 + c;
        f32x4 acc = {0.f, 0.f, 0.f, 0.f};
        #pragma unroll
        for (int ks = 0; ks < 4; ++ks) {
            bf16x8 bh = BH[(ctile * 4 + ks) * 64 + lane];
            bf16x8 bl = BL[(ctile * 4 + ks) * 64 + lane];
            acc = __builtin_amdgcn_mfma_f32_16x16x32_bf16(Ahi[ks], bh, acc, 0, 0, 0);
            acc = __builtin_amdgcn_mfma_f32_16x16x32_bf16(Alo[ks], bh, acc, 0, 0, 0);
            acc = __builtin_amdgcn_mfma_f32_16x16x32_bf16(Ahi[ks], bl, acc, 0, 0, 0);
        }
        int colc = ctile * 16 + m;
        #pragma unroll
        for (int reg = 0; reg < 4; ++reg) {
            int gr = row0 + quad * 4 + reg;
            if (gr < N)
                Y[(size_t)gr * N_FEAT + colc] = f2bf_rtne(acc[reg]);
        }
    }
}

#define ACC8(u) { acc[0] += __uint_as_float((u).x << 16); \
                  acc[1] += __uint_as_float((u).x & 0xffff0000u); \
                  acc[2] += __uint_as_float((u).y << 16); \
                  acc[3] += __uint_as_float((u).y & 0xffff0000u); \
                  acc[4] += __uint_as_float((u).z << 16); \
                  acc[5] += __uint_as_float((u).z & 0xffff0000u); \
                  acc[6] += __uint_as_float((u).w << 16); \
                  acc[7] += __uint_as_float((u).w & 0xffff0000u); }

// ---------------------------------------------------------------------------
// K4: pure gather-aggregate over Y (R16-proven: runs at ~HBM rate).
// ---------------------------------------------------------------------------
__global__ __launch_bounds__(128) void agg_kernel(const unsigned short* __restrict__ Y,
                                                  const int* __restrict__ elist,
                                                  const int2* __restrict__ offs,
                                                  const float* __restrict__ ri,
                                                  const float* __restrict__ bias,
                                                  float* __restrict__ out,
                                                  int N) {
    int tid  = threadIdx.x;
    int wave = tid >> 6, lane = tid & 63;
    int quad = lane >> 4, k16 = lane & 15;
    int node = blockIdx.x * 8 + wave * 4 + quad;
    if (node >= N) return;
    const uint4* yr = (const uint4*)Y;     // 16 granules (uint4) per 128-feat row
    int2 oe = offs[node];
    float rr = ri[node];
    float acc[8] = {0.f, 0.f, 0.f, 0.f, 0.f, 0.f, 0.f, 0.f};
    int j = oe.x, je = oe.y;
    for (; j + 8 <= je; j += 8) {
        int e0 = elist[j],     e1 = elist[j + 1];
        int e2 = elist[j + 2], e3 = elist[j + 3];
        int e4 = elist[j + 4], e5 = elist[j + 5];
        int e6 = elist[j + 6], e7 = elist[j + 7];
        uint4 u0 = yr[(size_t)e0 * 16 + k16];
        uint4 u1 = yr[(size_t)e1 * 16 + k16];
        uint4 u2 = yr[(size_t)e2 * 16 + k16];
        uint4 u3 = yr[(size_t)e3 * 16 + k16];
        uint4 u4 = yr[(size_t)e4 * 16 + k16];
        uint4 u5 = yr[(size_t)e5 * 16 + k16];
        uint4 u6 = yr[(size_t)e6 * 16 + k16];
        uint4 u7 = yr[(size_t)e7 * 16 + k16];
        ACC8(u0) ACC8(u1) ACC8(u2) ACC8(u3)
        ACC8(u4) ACC8(u5) ACC8(u6) ACC8(u7)
    }
    for (; j < je; ++j) {
        int e = elist[j];
        uint4 u = yr[(size_t)e * 16 + k16];
        ACC8(u)
    }
    int f0 = k16 * 8;
    const float4* bp = (const float4*)(bias + f0);
    float4 b0 = bp[0], b1 = bp[1];
    float4 o0, o1;
    o0.x = fmaxf(acc[0] * rr + b0.x, 0.f);
    o0.y = fmaxf(acc[1] * rr + b0.y, 0.f);
    o0.z = fmaxf(acc[2] * rr + b0.z, 0.f);
    o0.w = fmaxf(acc[3] * rr + b0.w, 0.f);
    o1.x = fmaxf(acc[4] * rr + b1.x, 0.f);
    o1.y = fmaxf(acc[5] * rr + b1.y, 0.f);
    o1.z = fmaxf(acc[6] * rr + b1.z, 0.f);
    o1.w = fmaxf(acc[7] * rr + b1.w, 0.f);
    float4* op = (float4*)(out + (size_t)node * N_FEAT + f0);
    op[0] = o0;
    op[1] = o1;
}

// ---------------------------------------------------------------------------
extern "C" void kernel_launch(void* const* d_in, const int* in_sizes, int n_in,
                              void* d_out, int out_size, void* d_ws, size_t ws_size,
                              hipStream_t stream) {
    const float* x      = (const float*)d_in[0];
    const int*   source = (const int*)d_in[1];
    const int*   target = (const int*)d_in[2];
    const float* W      = (const float*)d_in[3];
    const float* bias   = (const float*)d_in[4];
    float*       out    = (float*)d_out;

    const int N = in_sizes[0] / N_FEAT;   // 50000
    const int E = in_sizes[1];            // 800000

    const int NB   = (N + MAXRANGE - 1) >> BSHIFT;  // 196
    const int NBLK = (E + CHUNK - 1) / CHUNK;       // 391

    uintptr_t p = (uintptr_t)d_ws;
    auto carve = [&](size_t bytes) {
        p = (p + 255) & ~(uintptr_t)255;
        uintptr_t r = p;
        p += bytes;
        return (void*)r;
    };
    int*            curs    = (int*)carve((size_t)2 * NB * sizeof(int)); // curT|curS (memset)
    int*            curT    = curs;
    int*            curS    = curs + NB;
    unsigned int*   pairsT  = (unsigned int*)carve((size_t)NB * CAP * sizeof(unsigned int));
    int*            elist   = (int*)carve((size_t)NB * CAP * sizeof(int));
    unsigned char*  srcB    = (unsigned char*)carve((size_t)NB * CAP);
    float*          ri      = (float*)carve((size_t)N * sizeof(float));
    float*          so      = (float*)carve((size_t)N * sizeof(float));
    int2*           offs    = (int2*)carve((size_t)N * sizeof(int2));
    unsigned short* Y       = (unsigned short*)carve((size_t)N * N_FEAT * sizeof(unsigned short));
    unsigned short* Whi     = (unsigned short*)carve((size_t)N_FEAT * N_FEAT * sizeof(unsigned short));
    unsigned short* Wlo     = (unsigned short*)carve((size_t)N_FEAT * N_FEAT * sizeof(unsigned short));
    (void)ws_size; (void)n_in; (void)out_size;

    (void)hipMemsetAsync(curs, 0, (size_t)2 * NB * sizeof(int), stream);

    scatter_kernel<<<NBLK + 8, 256, 0, stream>>>(source, target, curT, curS, pairsT, srcB,
                                                 W, Whi, Wlo, E, NB, NBLK);
    prep_kernel<<<2 * NB, 256, 0, stream>>>(srcB, pairsT, curT, curS, so,
                                            offs, elist, ri, N, NB);
    ygemm_kernel<<<(N + 15) / 16, 256, 0, stream>>>(x, so, Whi, Wlo, Y, N);
    agg_kernel<<<(N + 7) / 8, 128, 0, stream>>>(Y, elist, offs, ri, bias, out, N);
}